// Round 2
// baseline (750.124 us; speedup 1.0000x reference)
//
#include <hip/hip_runtime.h>

// Problem constants: B=4, C=128, N=64, HID=1536, PROJ=768
// x: [4,128,64,64,64] fp32 (512 MiB). out: [4,192,768] fp32.
// ws layout: feat [768][128] fp32 | h [768][1536] fp32 | part [4][768][768] fp32

// ---------------- Stage 0: zero feat (atomic accumulation target) ----------------
__global__ __launch_bounds__(256)
void zero_feat_kernel(float* __restrict__ feat) {
    const int i = blockIdx.x * 256 + threadIdx.x;   // 96 blocks * 256 = 24576 float4
    ((float4*)feat)[i] = make_float4(0.f, 0.f, 0.f, 0.f);
}

// ---------------- Stage 1: plane reductions of x^2 ----------------
// Block = (bc, dchunk): 256 threads process 8 slices (128 KB) of cube bc.
// Within a slice (4096 floats = 1024 float4): thread t, load j in 0..3:
//   idx4 = t + 256*j  ->  h = 16*j + (t>>4)  (fixed per j), w4 = t&15 (fixed).
// So sum_w lives in 4 registers, sum_h in 4 registers; only the per-slice
// total (sum_d) needs a cross-lane reduce: one 6-shuffle wave reduce per 16 KB.
__global__ __launch_bounds__(256, 8)
void plane_reduce_kernel(const float* __restrict__ x, float* __restrict__ feat) {
    const int blk    = blockIdx.x;        // bc*8 + dchunk
    const int bc     = blk >> 3;
    const int dchunk = blk & 7;
    const int b      = bc >> 7;
    const int c      = bc & 127;
    const float4* __restrict__ xp =
        (const float4*)x + (size_t)bc * 65536 + (size_t)dchunk * 8192;

    const int t    = threadIdx.x;
    const int lane = t & 63;
    const int wv   = t >> 6;

    __shared__ float sd_lds[8][4];        // [slice][wave]
    __shared__ float sw_lds[4][64];       // [wave][w]

    float sw[4] = {0.f, 0.f, 0.f, 0.f};
    float sh[4] = {0.f, 0.f, 0.f, 0.f};

    #pragma unroll 2
    for (int s = 0; s < 8; ++s) {
        const float4* sp = xp + s * 1024;
        float4 v0 = sp[t];
        float4 v1 = sp[t + 256];
        float4 v2 = sp[t + 512];
        float4 v3 = sp[t + 768];

        float q0, q1, q2, q3, p;
        float ssl;
        q0 = v0.x * v0.x; q1 = v0.y * v0.y; q2 = v0.z * v0.z; q3 = v0.w * v0.w;
        sw[0] += q0; sw[1] += q1; sw[2] += q2; sw[3] += q3;
        p = (q0 + q1) + (q2 + q3); sh[0] += p; ssl = p;
        q0 = v1.x * v1.x; q1 = v1.y * v1.y; q2 = v1.z * v1.z; q3 = v1.w * v1.w;
        sw[0] += q0; sw[1] += q1; sw[2] += q2; sw[3] += q3;
        p = (q0 + q1) + (q2 + q3); sh[1] += p; ssl += p;
        q0 = v2.x * v2.x; q1 = v2.y * v2.y; q2 = v2.z * v2.z; q3 = v2.w * v2.w;
        sw[0] += q0; sw[1] += q1; sw[2] += q2; sw[3] += q3;
        p = (q0 + q1) + (q2 + q3); sh[2] += p; ssl += p;
        q0 = v3.x * v3.x; q1 = v3.y * v3.y; q2 = v3.z * v3.z; q3 = v3.w * v3.w;
        sw[0] += q0; sw[1] += q1; sw[2] += q2; sw[3] += q3;
        p = (q0 + q1) + (q2 + q3); sh[3] += p; ssl += p;

        #pragma unroll
        for (int off = 32; off; off >>= 1) ssl += __shfl_down(ssl, off, 64);
        if (lane == 0) sd_lds[s][wv] = ssl;
    }

    const float inv = 1.0f / 4096.0f;
    float* fb = feat + (size_t)b * 192 * 128 + c;

    // sum_h: reduce over the 16 lanes sharing (t>>4), i.e. groups of 16 lanes.
    #pragma unroll
    for (int j = 0; j < 4; ++j) {
        float v = sh[j];
        v += __shfl_down(v, 8, 16);
        v += __shfl_down(v, 4, 16);
        v += __shfl_down(v, 2, 16);
        v += __shfl_down(v, 1, 16);
        if ((lane & 15) == 0) {
            int h = 16 * j + (t >> 4);
            atomicAdd(&fb[(size_t)(64 + h) * 128], v * inv);
        }
    }

    // sum_w: reduce over lanes sharing (lane&15) within the wave, combine waves in LDS.
    #pragma unroll
    for (int comp = 0; comp < 4; ++comp) {
        float v = sw[comp];
        v += __shfl_down(v, 32, 64);
        v += __shfl_down(v, 16, 64);
        if (lane < 16) sw_lds[wv][4 * lane + comp] = v;
    }
    __syncthreads();

    if (t < 64) {
        float v = sw_lds[0][t] + sw_lds[1][t] + sw_lds[2][t] + sw_lds[3][t];
        atomicAdd(&fb[(size_t)(128 + t) * 128], v * inv);
    }
    if (t < 8) {
        float v = sd_lds[t][0] + sd_lds[t][1] + sd_lds[t][2] + sd_lds[t][3];
        int d = dchunk * 8 + t;
        fb[(size_t)d * 128] = v * inv;    // block owns (bc, d): direct store
    }
}

// ---------------- GEMM1: h = relu(feat @ W1 + b1) ----------------
// M=768, K=128, N=1536. 64x64 tile, full K in LDS, 4x4 per thread.
__global__ __launch_bounds__(256, 2)
void gemm1_relu_kernel(const float* __restrict__ feat, const float* __restrict__ W1,
                       const float* __restrict__ b1, float* __restrict__ hbuf) {
    __shared__ float AsT[128][68];  // [k][m], padded
    __shared__ float Bs[128][68];   // [k][n]
    const int t  = threadIdx.x;
    const int n0 = blockIdx.x * 64;
    const int m0 = blockIdx.y * 64;

    #pragma unroll
    for (int r = 0; r < 8; ++r) {       // A tile: 64 rows x 128 k
        int idx = t + 256 * r;          // 0..2047 float4s
        int row = idx >> 5;
        int kv  = idx & 31;
        float4 a = *(const float4*)(feat + (size_t)(m0 + row) * 128 + kv * 4);
        AsT[kv * 4 + 0][row] = a.x;
        AsT[kv * 4 + 1][row] = a.y;
        AsT[kv * 4 + 2][row] = a.z;
        AsT[kv * 4 + 3][row] = a.w;
    }
    #pragma unroll
    for (int r = 0; r < 8; ++r) {       // B tile: 128 k x 64 n
        int idx = t + 256 * r;
        int kr = idx >> 4;
        int nv = idx & 15;
        *(float4*)&Bs[kr][nv * 4] =
            *(const float4*)(W1 + (size_t)kr * 1536 + n0 + nv * 4);
    }
    __syncthreads();

    const int tm = t >> 4, tn = t & 15;
    float acc[4][4] = {};
    #pragma unroll 4
    for (int k = 0; k < 128; ++k) {
        float4 a  = *(const float4*)&AsT[k][tm * 4];
        float4 bv = *(const float4*)&Bs[k][tn * 4];
        float av[4] = {a.x, a.y, a.z, a.w};
        float bb[4] = {bv.x, bv.y, bv.z, bv.w};
        #pragma unroll
        for (int i = 0; i < 4; ++i)
            #pragma unroll
            for (int j = 0; j < 4; ++j)
                acc[i][j] += av[i] * bb[j];
    }

    float4 bias = *(const float4*)(b1 + n0 + tn * 4);
    float bb[4] = {bias.x, bias.y, bias.z, bias.w};
    #pragma unroll
    for (int i = 0; i < 4; ++i) {
        float4 o;
        o.x = fmaxf(acc[i][0] + bb[0], 0.f);
        o.y = fmaxf(acc[i][1] + bb[1], 0.f);
        o.z = fmaxf(acc[i][2] + bb[2], 0.f);
        o.w = fmaxf(acc[i][3] + bb[3], 0.f);
        *(float4*)(hbuf + (size_t)(m0 + tm * 4 + i) * 1536 + n0 + tn * 4) = o;
    }
}

// ---------------- GEMM2 (k-split partials): part[s] = h[:,ks] @ W2[ks,:] ----------------
__global__ __launch_bounds__(256, 4)
void gemm2_partial_kernel(const float* __restrict__ hbuf, const float* __restrict__ W2,
                          float* __restrict__ part) {
    __shared__ float AsT[32][68];
    __shared__ float Bs[32][68];
    const int t  = threadIdx.x;
    const int n0 = blockIdx.x * 64;
    const int m0 = blockIdx.y * 64;
    const int k0 = blockIdx.z * 384;
    const int tm = t >> 4, tn = t & 15;
    float acc[4][4] = {};

    for (int kk = 0; kk < 384; kk += 32) {
        const int kb = k0 + kk;
        #pragma unroll
        for (int r = 0; r < 2; ++r) {   // A: 64 rows x 32 k
            int idx = t + 256 * r;
            int row = idx >> 3;
            int kv  = idx & 7;
            float4 a = *(const float4*)(hbuf + (size_t)(m0 + row) * 1536 + kb + kv * 4);
            AsT[kv * 4 + 0][row] = a.x;
            AsT[kv * 4 + 1][row] = a.y;
            AsT[kv * 4 + 2][row] = a.z;
            AsT[kv * 4 + 3][row] = a.w;
        }
        #pragma unroll
        for (int r = 0; r < 2; ++r) {   // B: 32 k x 64 n
            int idx = t + 256 * r;
            int kr = idx >> 4;
            int nv = idx & 15;
            *(float4*)&Bs[kr][nv * 4] =
                *(const float4*)(W2 + (size_t)(kb + kr) * 768 + n0 + nv * 4);
        }
        __syncthreads();
        #pragma unroll
        for (int k = 0; k < 32; ++k) {
            float4 a  = *(const float4*)&AsT[k][tm * 4];
            float4 bv = *(const float4*)&Bs[k][tn * 4];
            float av[4] = {a.x, a.y, a.z, a.w};
            float bb[4] = {bv.x, bv.y, bv.z, bv.w};
            #pragma unroll
            for (int i = 0; i < 4; ++i)
                #pragma unroll
                for (int j = 0; j < 4; ++j)
                    acc[i][j] += av[i] * bb[j];
        }
        __syncthreads();
    }

    float* po = part + (size_t)blockIdx.z * (768 * 768);
    #pragma unroll
    for (int i = 0; i < 4; ++i) {
        float4 o;
        o.x = acc[i][0]; o.y = acc[i][1]; o.z = acc[i][2]; o.w = acc[i][3];
        *(float4*)(po + (size_t)(m0 + tm * 4 + i) * 768 + n0 + tn * 4) = o;
    }
}

// ---------------- Reduce partials + bias ----------------
__global__ __launch_bounds__(256)
void reduce_bias_kernel(const float* __restrict__ part, const float* __restrict__ b2,
                        float* __restrict__ out) {
    const int idx = blockIdx.x * 256 + threadIdx.x;   // float4 index
    const float4* p = (const float4*)part;
    float4 s0 = p[idx];
    float4 s1 = p[idx + 147456];
    float4 s2 = p[idx + 2 * 147456];
    float4 s3 = p[idx + 3 * 147456];
    const int col4 = idx % 192;
    float4 bb = ((const float4*)b2)[col4];
    float4 o;
    o.x = s0.x + s1.x + s2.x + s3.x + bb.x;
    o.y = s0.y + s1.y + s2.y + s3.y + bb.y;
    o.z = s0.z + s1.z + s2.z + s3.z + bb.z;
    o.w = s0.w + s1.w + s2.w + s3.w + bb.w;
    ((float4*)out)[idx] = o;
}

extern "C" void kernel_launch(void* const* d_in, const int* in_sizes, int n_in,
                              void* d_out, int out_size, void* d_ws, size_t ws_size,
                              hipStream_t stream) {
    const float* x  = (const float*)d_in[0];
    const float* W1 = (const float*)d_in[1];
    const float* b1 = (const float*)d_in[2];
    const float* W2 = (const float*)d_in[3];
    const float* b2 = (const float*)d_in[4];
    float* out  = (float*)d_out;
    float* feat = (float*)d_ws;             // 768*128
    float* hbuf = feat + 768 * 128;         // 768*1536
    float* part = hbuf + 768 * 1536;        // 4*768*768

    hipLaunchKernelGGL(zero_feat_kernel, dim3(96), dim3(256), 0, stream, feat);
    hipLaunchKernelGGL(plane_reduce_kernel, dim3(4096), dim3(256), 0, stream, x, feat);
    hipLaunchKernelGGL(gemm1_relu_kernel, dim3(24, 12), dim3(256), 0, stream, feat, W1, b1, hbuf);
    hipLaunchKernelGGL(gemm2_partial_kernel, dim3(12, 12, 4), dim3(256), 0, stream, hbuf, W2, part);
    hipLaunchKernelGGL(reduce_bias_kernel, dim3(576), dim3(256), 0, stream, part, b2, out);
}

// Round 3
// 746.953 us; speedup vs baseline: 1.0042x; 1.0042x over previous
//
#include <hip/hip_runtime.h>

// Problem constants: B=4, C=128, N=64, HID=1536, PROJ=768
// x: [4,128,64,64,64] fp32 (512 MiB). out: [4,192,768] fp32.
// ws layout: feat [768][128] | h [768][1536] | part [8][768][768]  (~24 MB of 2 GiB ws)

// ---------------- Stage 0: zero feat (atomic accumulation target) ----------------
__global__ __launch_bounds__(256)
void zero_feat_kernel(float* __restrict__ feat) {
    const int i = blockIdx.x * 256 + threadIdx.x;   // 96 blocks * 256 = 24576 float4
    ((float4*)feat)[i] = make_float4(0.f, 0.f, 0.f, 0.f);
}

// ---------------- Stage 1: plane reductions of x^2 (UNCHANGED from R2) ----------------
__global__ __launch_bounds__(256, 8)
void plane_reduce_kernel(const float* __restrict__ x, float* __restrict__ feat) {
    const int blk    = blockIdx.x;        // bc*8 + dchunk
    const int bc     = blk >> 3;
    const int dchunk = blk & 7;
    const int b      = bc >> 7;
    const int c      = bc & 127;
    const float4* __restrict__ xp =
        (const float4*)x + (size_t)bc * 65536 + (size_t)dchunk * 8192;

    const int t    = threadIdx.x;
    const int lane = t & 63;
    const int wv   = t >> 6;

    __shared__ float sd_lds[8][4];        // [slice][wave]
    __shared__ float sw_lds[4][64];       // [wave][w]

    float sw[4] = {0.f, 0.f, 0.f, 0.f};
    float sh[4] = {0.f, 0.f, 0.f, 0.f};

    #pragma unroll 2
    for (int s = 0; s < 8; ++s) {
        const float4* sp = xp + s * 1024;
        float4 v0 = sp[t];
        float4 v1 = sp[t + 256];
        float4 v2 = sp[t + 512];
        float4 v3 = sp[t + 768];

        float q0, q1, q2, q3, p;
        float ssl;
        q0 = v0.x * v0.x; q1 = v0.y * v0.y; q2 = v0.z * v0.z; q3 = v0.w * v0.w;
        sw[0] += q0; sw[1] += q1; sw[2] += q2; sw[3] += q3;
        p = (q0 + q1) + (q2 + q3); sh[0] += p; ssl = p;
        q0 = v1.x * v1.x; q1 = v1.y * v1.y; q2 = v1.z * v1.z; q3 = v1.w * v1.w;
        sw[0] += q0; sw[1] += q1; sw[2] += q2; sw[3] += q3;
        p = (q0 + q1) + (q2 + q3); sh[1] += p; ssl += p;
        q0 = v2.x * v2.x; q1 = v2.y * v2.y; q2 = v2.z * v2.z; q3 = v2.w * v2.w;
        sw[0] += q0; sw[1] += q1; sw[2] += q2; sw[3] += q3;
        p = (q0 + q1) + (q2 + q3); sh[2] += p; ssl += p;
        q0 = v3.x * v3.x; q1 = v3.y * v3.y; q2 = v3.z * v3.z; q3 = v3.w * v3.w;
        sw[0] += q0; sw[1] += q1; sw[2] += q2; sw[3] += q3;
        p = (q0 + q1) + (q2 + q3); sh[3] += p; ssl += p;

        #pragma unroll
        for (int off = 32; off; off >>= 1) ssl += __shfl_down(ssl, off, 64);
        if (lane == 0) sd_lds[s][wv] = ssl;
    }

    const float inv = 1.0f / 4096.0f;
    float* fb = feat + (size_t)b * 192 * 128 + c;

    #pragma unroll
    for (int j = 0; j < 4; ++j) {
        float v = sh[j];
        v += __shfl_down(v, 8, 16);
        v += __shfl_down(v, 4, 16);
        v += __shfl_down(v, 2, 16);
        v += __shfl_down(v, 1, 16);
        if ((lane & 15) == 0) {
            int h = 16 * j + (t >> 4);
            atomicAdd(&fb[(size_t)(64 + h) * 128], v * inv);
        }
    }

    #pragma unroll
    for (int comp = 0; comp < 4; ++comp) {
        float v = sw[comp];
        v += __shfl_down(v, 32, 64);
        v += __shfl_down(v, 16, 64);
        if (lane < 16) sw_lds[wv][4 * lane + comp] = v;
    }
    __syncthreads();

    if (t < 64) {
        float v = sw_lds[0][t] + sw_lds[1][t] + sw_lds[2][t] + sw_lds[3][t];
        atomicAdd(&fb[(size_t)(128 + t) * 128], v * inv);
    }
    if (t < 8) {
        float v = sd_lds[t][0] + sd_lds[t][1] + sd_lds[t][2] + sd_lds[t][3];
        int d = dchunk * 8 + t;
        fb[(size_t)d * 128] = v * inv;
    }
}

// ---------------- GEMM1: h = relu(feat @ W1 + b1) (UNCHANGED) ----------------
__global__ __launch_bounds__(256, 2)
void gemm1_relu_kernel(const float* __restrict__ feat, const float* __restrict__ W1,
                       const float* __restrict__ b1, float* __restrict__ hbuf) {
    __shared__ float AsT[128][68];
    __shared__ float Bs[128][68];
    const int t  = threadIdx.x;
    const int n0 = blockIdx.x * 64;
    const int m0 = blockIdx.y * 64;

    #pragma unroll
    for (int r = 0; r < 8; ++r) {
        int idx = t + 256 * r;
        int row = idx >> 5;
        int kv  = idx & 31;
        float4 a = *(const float4*)(feat + (size_t)(m0 + row) * 128 + kv * 4);
        AsT[kv * 4 + 0][row] = a.x;
        AsT[kv * 4 + 1][row] = a.y;
        AsT[kv * 4 + 2][row] = a.z;
        AsT[kv * 4 + 3][row] = a.w;
    }
    #pragma unroll
    for (int r = 0; r < 8; ++r) {
        int idx = t + 256 * r;
        int kr = idx >> 4;
        int nv = idx & 15;
        *(float4*)&Bs[kr][nv * 4] =
            *(const float4*)(W1 + (size_t)kr * 1536 + n0 + nv * 4);
    }
    __syncthreads();

    const int tm = t >> 4, tn = t & 15;
    float acc[4][4] = {};
    #pragma unroll 4
    for (int k = 0; k < 128; ++k) {
        float4 a  = *(const float4*)&AsT[k][tm * 4];
        float4 bv = *(const float4*)&Bs[k][tn * 4];
        float av[4] = {a.x, a.y, a.z, a.w};
        float bb[4] = {bv.x, bv.y, bv.z, bv.w};
        #pragma unroll
        for (int i = 0; i < 4; ++i)
            #pragma unroll
            for (int j = 0; j < 4; ++j)
                acc[i][j] += av[i] * bb[j];
    }

    float4 bias = *(const float4*)(b1 + n0 + tn * 4);
    float bb[4] = {bias.x, bias.y, bias.z, bias.w};
    #pragma unroll
    for (int i = 0; i < 4; ++i) {
        float4 o;
        o.x = fmaxf(acc[i][0] + bb[0], 0.f);
        o.y = fmaxf(acc[i][1] + bb[1], 0.f);
        o.z = fmaxf(acc[i][2] + bb[2], 0.f);
        o.w = fmaxf(acc[i][3] + bb[3], 0.f);
        *(float4*)(hbuf + (size_t)(m0 + tm * 4 + i) * 1536 + n0 + tn * 4) = o;
    }
}

// ---------------- GEMM2 (k-split 8): part[s] = h[:,ks] @ W2[ks,:] ----------------
// grid (12,12,8) = 1152 blocks (4.5/CU) for load balance; 192 k per block.
__global__ __launch_bounds__(256, 4)
void gemm2_partial_kernel(const float* __restrict__ hbuf, const float* __restrict__ W2,
                          float* __restrict__ part) {
    __shared__ float AsT[32][68];
    __shared__ float Bs[32][68];
    const int t  = threadIdx.x;
    const int n0 = blockIdx.x * 64;
    const int m0 = blockIdx.y * 64;
    const int k0 = blockIdx.z * 192;
    const int tm = t >> 4, tn = t & 15;
    float acc[4][4] = {};

    for (int kk = 0; kk < 192; kk += 32) {
        const int kb = k0 + kk;
        #pragma unroll
        for (int r = 0; r < 2; ++r) {   // A: 64 rows x 32 k
            int idx = t + 256 * r;
            int row = idx >> 3;
            int kv  = idx & 7;
            float4 a = *(const float4*)(hbuf + (size_t)(m0 + row) * 1536 + kb + kv * 4);
            AsT[kv * 4 + 0][row] = a.x;
            AsT[kv * 4 + 1][row] = a.y;
            AsT[kv * 4 + 2][row] = a.z;
            AsT[kv * 4 + 3][row] = a.w;
        }
        #pragma unroll
        for (int r = 0; r < 2; ++r) {   // B: 32 k x 64 n
            int idx = t + 256 * r;
            int kr = idx >> 4;
            int nv = idx & 15;
            *(float4*)&Bs[kr][nv * 4] =
                *(const float4*)(W2 + (size_t)(kb + kr) * 768 + n0 + nv * 4);
        }
        __syncthreads();
        #pragma unroll
        for (int k = 0; k < 32; ++k) {
            float4 a  = *(const float4*)&AsT[k][tm * 4];
            float4 bv = *(const float4*)&Bs[k][tn * 4];
            float av[4] = {a.x, a.y, a.z, a.w};
            float bb[4] = {bv.x, bv.y, bv.z, bv.w};
            #pragma unroll
            for (int i = 0; i < 4; ++i)
                #pragma unroll
                for (int j = 0; j < 4; ++j)
                    acc[i][j] += av[i] * bb[j];
        }
        __syncthreads();
    }

    float* po = part + (size_t)blockIdx.z * (768 * 768);
    #pragma unroll
    for (int i = 0; i < 4; ++i) {
        float4 o;
        o.x = acc[i][0]; o.y = acc[i][1]; o.z = acc[i][2]; o.w = acc[i][3];
        *(float4*)(po + (size_t)(m0 + tm * 4 + i) * 768 + n0 + tn * 4) = o;
    }
}

// ---------------- Reduce 8 partials + bias ----------------
__global__ __launch_bounds__(256)
void reduce_bias_kernel(const float* __restrict__ part, const float* __restrict__ b2,
                        float* __restrict__ out) {
    const int idx = blockIdx.x * 256 + threadIdx.x;   // float4 index, 0..147455
    const float4* p = (const float4*)part;
    float4 a0 = p[idx];
    float4 a1 = p[idx + 1 * 147456];
    float4 a2 = p[idx + 2 * 147456];
    float4 a3 = p[idx + 3 * 147456];
    float4 a4 = p[idx + 4 * 147456];
    float4 a5 = p[idx + 5 * 147456];
    float4 a6 = p[idx + 6 * 147456];
    float4 a7 = p[idx + 7 * 147456];
    const int col4 = idx % 192;
    float4 bb = ((const float4*)b2)[col4];
    float4 o;
    o.x = ((a0.x + a1.x) + (a2.x + a3.x)) + ((a4.x + a5.x) + (a6.x + a7.x)) + bb.x;
    o.y = ((a0.y + a1.y) + (a2.y + a3.y)) + ((a4.y + a5.y) + (a6.y + a7.y)) + bb.y;
    o.z = ((a0.z + a1.z) + (a2.z + a3.z)) + ((a4.z + a5.z) + (a6.z + a7.z)) + bb.z;
    o.w = ((a0.w + a1.w) + (a2.w + a3.w)) + ((a4.w + a5.w) + (a6.w + a7.w)) + bb.w;
    ((float4*)out)[idx] = o;
}

extern "C" void kernel_launch(void* const* d_in, const int* in_sizes, int n_in,
                              void* d_out, int out_size, void* d_ws, size_t ws_size,
                              hipStream_t stream) {
    const float* x  = (const float*)d_in[0];
    const float* W1 = (const float*)d_in[1];
    const float* b1 = (const float*)d_in[2];
    const float* W2 = (const float*)d_in[3];
    const float* b2 = (const float*)d_in[4];
    float* out  = (float*)d_out;
    float* feat = (float*)d_ws;             // 768*128
    float* hbuf = feat + 768 * 128;         // 768*1536
    float* part = hbuf + 768 * 1536;        // 8*768*768

    hipLaunchKernelGGL(zero_feat_kernel, dim3(96), dim3(256), 0, stream, feat);
    hipLaunchKernelGGL(plane_reduce_kernel, dim3(4096), dim3(256), 0, stream, x, feat);
    hipLaunchKernelGGL(gemm1_relu_kernel, dim3(24, 12), dim3(256), 0, stream, feat, W1, b1, hbuf);
    hipLaunchKernelGGL(gemm2_partial_kernel, dim3(12, 12, 8), dim3(256), 0, stream, hbuf, W2, part);
    hipLaunchKernelGGL(reduce_bias_kernel, dim3(576), dim3(256), 0, stream, part, b2, out);
}